// Round 4
// baseline (605.958 us; speedup 1.0000x reference)
//
#include <hip/hip_runtime.h>

#define BB 2
#define LL 2048
#define EE 1024
#define HH 16
#define HDD 64

typedef __bf16 bf16x8 __attribute__((ext_vector_type(8)));
typedef float f32x4 __attribute__((ext_vector_type(4)));

__device__ __forceinline__ unsigned short f2bf(float f) {
  unsigned int x = __float_as_uint(f);
  return (unsigned short)((x + 0x7FFFu + ((x >> 16) & 1u)) >> 16);  // RNE
}

__device__ __forceinline__ float bf2f(unsigned short u) {
  return __uint_as_float((unsigned int)u << 16);
}

__device__ __forceinline__ void load_lds16(const void* g, void* l) {
  __builtin_amdgcn_global_load_lds(
      (const __attribute__((address_space(1))) void*)g,
      (__attribute__((address_space(3))) void*)l, 16, 0, 0);
}

// ---------------- prelude ----------------------------------------------------
// blocks 0..255   : column sums of key/value (16-row chunks, heavy -> first)
// blocks 256..1535: grid-stride cast fp32->bf16 of q, pe, Wq, Wp
#define SUMKV_BLOCKS 256
#define CAST_BLOCKS 1280
#define CAST_STRIDE (CAST_BLOCKS * 256)   // 327680 float4s per sweep
__global__ __launch_bounds__(256) void prelude_kernel(
    const float* __restrict__ q, const float* __restrict__ pe,
    const float* __restrict__ wq, const float* __restrict__ wp,
    unsigned short* __restrict__ q16, unsigned short* __restrict__ pe16,
    unsigned short* __restrict__ wq16, unsigned short* __restrict__ wp16,
    const float* __restrict__ key, const float* __restrict__ value,
    float* __restrict__ keysum, float* __restrict__ valsum) {
  if (blockIdx.x < SUMKV_BLOCKS) {
    int blk2 = blockIdx.x;                // (b, 128 chunks of 16 rows)
    int b = blk2 >> 7, ch = blk2 & 127;
    int tid = threadIdx.x;                // float4 index within E
    const float4* k4 = (const float4*)(key   + ((size_t)b * LL + ch * 16) * EE);
    const float4* v4 = (const float4*)(value + ((size_t)b * LL + ch * 16) * EE);
    float4 ak = make_float4(0.f, 0.f, 0.f, 0.f);
    float4 av = make_float4(0.f, 0.f, 0.f, 0.f);
#pragma unroll 8
    for (int i = 0; i < 16; i++) {
      float4 kk = k4[i * 256 + tid];
      float4 vv = v4[i * 256 + tid];
      ak.x += kk.x; ak.y += kk.y; ak.z += kk.z; ak.w += kk.w;
      av.x += vv.x; av.y += vv.y; av.z += vv.z; av.w += vv.w;
    }
    int e = tid * 4;
    atomicAdd(&keysum[b * EE + e + 0], ak.x);
    atomicAdd(&keysum[b * EE + e + 1], ak.y);
    atomicAdd(&keysum[b * EE + e + 2], ak.z);
    atomicAdd(&keysum[b * EE + e + 3], ak.w);
    atomicAdd(&valsum[b * EE + e + 0], av.x);
    atomicAdd(&valsum[b * EE + e + 1], av.y);
    atomicAdd(&valsum[b * EE + e + 2], av.z);
    atomicAdd(&valsum[b * EE + e + 3], av.w);
  } else {
    const int NQ4 = BB * LL * EE / 4;   // 1048576 float4s each for q, pe
    const int NW4 = EE * EE / 4;        // 262144 each for wq, wp
    int t = (blockIdx.x - SUMKV_BLOCKS) * 256 + threadIdx.x;
    float4 v[8]; unsigned short* dst[8]; int off[8];
#pragma unroll
    for (int k = 0; k < 8; k++) {
      int i = t + k * CAST_STRIDE;      // total = 8*327680 = 2621440 exactly
      const float* src;
      if (i < NQ4)                { src = q;  dst[k] = q16;  off[k] = i; }
      else if (i < 2 * NQ4)       { src = pe; dst[k] = pe16; off[k] = i - NQ4; }
      else if (i < 2 * NQ4 + NW4) { src = wq; dst[k] = wq16; off[k] = i - 2 * NQ4; }
      else                        { src = wp; dst[k] = wp16; off[k] = i - 2 * NQ4 - NW4; }
      v[k] = ((const float4*)src)[off[k]];
    }
#pragma unroll
    for (int k = 0; k < 8; k++) {
      ushort4 u;
      u.x = f2bf(v[k].x); u.y = f2bf(v[k].y); u.z = f2bf(v[k].z); u.w = f2bf(v[k].w);
      ((ushort4*)dst[k])[off[k]] = u;
    }
  }
}

// ---------------- merged small projections -----------------------------------
// blocks 0..31 : per (b,h): Vproj slice (64 dots) into LDS, then W2[b,h,0:1024]
// blocks 32..39: Kproj[b,ep] = keysum[b,:].Wk[ep,:] + L*bk[ep]  (wave/output)
__global__ __launch_bounds__(256) void small_kernel(
    const float* __restrict__ keysum, const float* __restrict__ valsum,
    const float* __restrict__ Wk, const float* __restrict__ bk,
    const float* __restrict__ Wv, const float* __restrict__ bv,
    const float* __restrict__ Wo, float* __restrict__ Kproj,
    float* __restrict__ W2) {
  __shared__ float vsh[HDD];
  int wv = threadIdx.x >> 6, lane = threadIdx.x & 63;
  int blk = blockIdx.x;
  if (blk < 32) {
    int b = blk >> 4, h = blk & 15;
    // wave wv computes Vproj for d = wv*16 .. wv*16+15
    for (int dd = 0; dd < 16; dd++) {
      int d = wv * 16 + dd;
      int row = h * HDD + d;
      float acc = 0.f;
      for (int k = lane; k < EE; k += 64)
        acc += valsum[b * EE + k] * Wv[(size_t)row * EE + k];
      for (int off = 32; off; off >>= 1) acc += __shfl_down(acc, off, 64);
      if (lane == 0) vsh[d] = acc + (float)LL * bv[row];
    }
    __syncthreads();
    // W2[b,h,e]: 4 consecutive e per thread; each lane streams 256 B of Wo
    float4 vs[16];
#pragma unroll
    for (int i = 0; i < 16; i++) vs[i] = ((const float4*)vsh)[i];
#pragma unroll
    for (int j = 0; j < 4; j++) {
      int e = threadIdx.x * 4 + j;
      const float4* wo = (const float4*)(Wo + (size_t)e * EE + h * HDD);
      float acc = 0.f;
#pragma unroll
      for (int i = 0; i < 16; i++) {
        float4 w = wo[i];
        acc += vs[i].x * w.x + vs[i].y * w.y + vs[i].z * w.z + vs[i].w * w.w;
      }
      W2[((size_t)b * HH + h) * EE + e] = acc;
    }
  } else {
    int wslot = (blk - 32) * 4 + wv;      // 0..31, 64 outputs per wave
    for (int r = 0; r < 64; r++) {
      int idx = wslot * 64 + r;           // 0..2047
      int b = idx >> 10, ep = idx & (EE - 1);
      float acc = 0.f;
      for (int k = lane; k < EE; k += 64)
        acc += keysum[b * EE + k] * Wk[(size_t)ep * EE + k];
      for (int off = 32; off; off >>= 1) acc += __shfl_down(acc, off, 64);
      if (lane == 0) Kproj[b * EE + ep] = acc + (float)LL * bk[ep];
    }
  }
}

// ---------------- bf16 MFMA GEMM: Out[M,N] = X[M,K] @ W[N,K]^T (+bias) -------
// 128x128 tile, BK=32, global_load_lds width=16 staging (m97 structure).
// z=0 -> q projection (+bq); z=1 -> r projection + fused chunk row-sums.
// Outputs stored as bf16 (halves round-trip traffic; chunks stay fp32).
__global__ __launch_bounds__(256) void gemm_kernel(
    const unsigned short* __restrict__ q16, const unsigned short* __restrict__ wq16,
    const float* __restrict__ bq, unsigned short* __restrict__ qout,
    const unsigned short* __restrict__ pe16, const unsigned short* __restrict__ wp16,
    unsigned short* __restrict__ rout, float* __restrict__ chunks) {
  const int K = EE, N = EE;
  const unsigned short* X; const unsigned short* W; const float* bias;
  unsigned short* Out;
  if (blockIdx.z == 0) { X = q16;  W = wq16; bias = bq;      Out = qout; }
  else                 { X = pe16; W = wp16; bias = nullptr; Out = rout; }

  __shared__ __align__(16) unsigned short As[128 * 32];  // 8 KB
  __shared__ __align__(16) unsigned short Bs[128 * 32];

  const int tid = threadIdx.x;
  const int lane = tid & 63;
  const int wv = tid >> 6;
  const int wr = wv >> 1, wc = wv & 1;
  const int n0 = blockIdx.x * 128;
  const int m0 = blockIdx.y * 128;

  // staging: lane l of wave wv -> LDS ushort idx wv*512 + l*8 == row-major
  //   row = wv*16 + l/4, col = (l%4)*8 of a [128 x 32] tile (no padding)
  const int srow = wv * 16 + (lane >> 2);
  const int scol = (lane & 3) * 8;
  const unsigned short* gA = X + (size_t)(m0 + srow) * K + scol;
  const unsigned short* gB = W + (size_t)(n0 + srow) * K + scol;
  unsigned short* sA = As + wv * 512;   // wave-uniform base
  unsigned short* sB = Bs + wv * 512;

  f32x4 acc[4][4];
#pragma unroll
  for (int i = 0; i < 4; i++)
#pragma unroll
    for (int j = 0; j < 4; j++) acc[i][j] = (f32x4)0.0f;

  const int arow = wr * 64 + (lane & 15);
  const int brow = wc * 64 + (lane & 15);
  const int koff = (lane >> 4) * 8;

  for (int kk = 0; kk < K; kk += 32) {
    load_lds16(gA + kk,                   sA);
    load_lds16(gA + kk + (size_t)64 * K,  sA + 2048);
    load_lds16(gB + kk,                   sB);
    load_lds16(gB + kk + (size_t)64 * K,  sB + 2048);
    __syncthreads();
    bf16x8 af[4], bf[4];
#pragma unroll
    for (int i = 0; i < 4; i++) af[i] = *(const bf16x8*)&As[(arow + i * 16) * 32 + koff];
#pragma unroll
    for (int j = 0; j < 4; j++) bf[j] = *(const bf16x8*)&Bs[(brow + j * 16) * 32 + koff];
#pragma unroll
    for (int i = 0; i < 4; i++)
#pragma unroll
      for (int j = 0; j < 4; j++)
        acc[i][j] = __builtin_amdgcn_mfma_f32_16x16x32_bf16(af[i], bf[j], acc[i][j], 0, 0, 0);
    __syncthreads();
  }

  // epilogue: C/D layout col=lane&15, row=(lane>>4)*4+g  [verified m89/m91]
  const int rbase = m0 + wr * 64 + (lane >> 4) * 4;
  const int cbase = n0 + wc * 64 + (lane & 15);
#pragma unroll
  for (int i = 0; i < 4; i++) {
#pragma unroll
    for (int j = 0; j < 4; j++) {
      int col = cbase + j * 16;
      float badd = bias ? bias[col] : 0.f;
#pragma unroll
      for (int g = 0; g < 4; g++) {
        int row = rbase + i * 16 + g;
        Out[(size_t)row * N + col] = f2bf(acc[i][j][g] + badd);
      }
    }
  }

  // fused scan stage-1 for the r projection: 32-row chunk column sums (fp32).
  // Each (chunk, col) is owned by exactly one wave of one block -> plain store.
  if (blockIdx.z == 1) {
    int b = m0 >> 11;
    int ch0 = ((m0 & (LL - 1)) >> 5) + wr * 2;
#pragma unroll
    for (int cp = 0; cp < 2; cp++) {
#pragma unroll
      for (int j = 0; j < 4; j++) {
        float s = 0.f;
#pragma unroll
        for (int i = cp * 2; i < cp * 2 + 2; i++)
#pragma unroll
          for (int g = 0; g < 4; g++) s += acc[i][j][g];
        s += __shfl_down(s, 32, 64);
        s += __shfl_down(s, 16, 64);
        if (lane < 16) {
          int col = n0 + wc * 64 + j * 16 + lane;
          chunks[((size_t)b * 64 + ch0 + cp) * EE + col] = s;
        }
      }
    }
  }
}

// ---------------- fused scan + score ----------------------------------------
// P[m] = prefix of r rows (in registers).  D[m] = (q_{L-1-m}+V) . P[m]
// S1[p] = (q_p+U).Kproj + (q_p+V).P[L]     (per-head dots over 64 lanes)
// grid (4 head-groups, 64 chunks, BB), block 256. qbuf/rbuf are bf16.
__global__ __launch_bounds__(256) void scan2f_kernel(
    const unsigned short* __restrict__ qbuf, const unsigned short* __restrict__ rbuf,
    const float* __restrict__ chunks, const float* __restrict__ Kproj,
    const float* __restrict__ U, const float* __restrict__ V,
    float* __restrict__ S1, float* __restrict__ Dbuf) {
  int tid = threadIdx.x, lane = tid & 63;
  int hg = blockIdx.x, ch = blockIdx.y, b = blockIdx.z;
  int e = hg * 256 + tid;
  int h = hg * 4 + (tid >> 6);
  float pre = 0.f, tot = 0.f;
  for (int c = 0; c < 64; c++) {           // 512 KB buffer, L2-resident
    float cs = chunks[((size_t)b * 64 + c) * EE + e];
    tot += cs;
    if (c < ch) pre += cs;
  }
  float kp = Kproj[b * EE + e], Ue = U[e], Ve = V[e];
  float run = pre;                          // == P[ch*32][e]
  size_t hoff = ((size_t)b * HH + h) * LL;
#pragma unroll 4
  for (int i = 0; i < 32; i++) {
    int m = ch * 32 + i;
    int p = LL - 1 - m;
    float qv = bf2f(qbuf[((size_t)b * LL + p) * EE + e]);
    float rv = bf2f(rbuf[((size_t)b * LL + m) * EE + e]);
    float tq = qv + Ve;
    float d = tq * run;                     // run == P[m]
    float s = tq * tot + (qv + Ue) * kp;
#pragma unroll
    for (int off = 32; off; off >>= 1) {
      d += __shfl_down(d, off, 64);
      s += __shfl_down(s, off, 64);
    }
    if (lane == 0) { Dbuf[hoff + m] = d; S1[hoff + p] = s; }
    run += rv;
  }
}

// ---------------- output: out[b,p,:] = sum_h S[b,h,p]*W2[b,h,:] + bo ---------
// S[b,h,p] = (S1[p] - D[L-1-p] + D[L-2-p]) / 32
__global__ __launch_bounds__(256) void out_kernel(
    const float* __restrict__ S1, const float* __restrict__ Dbuf,
    const float* __restrict__ W2, const float* __restrict__ bo,
    float* __restrict__ out) {
  int row = blockIdx.x;                   // [0, BB*LL)
  int b = row >> 11, p = row & (LL - 1);
  __shared__ float sh[HH];
  if (threadIdx.x < HH) {
    int h = threadIdx.x;
    size_t hoff = ((size_t)b * HH + h) * LL;
    float s1 = S1[hoff + p];
    float d1 = Dbuf[hoff + (LL - 1 - p)];
    float d2 = (p == LL - 1) ? 0.f : Dbuf[hoff + (LL - 2 - p)];
    sh[h] = (s1 - d1 + d2) * (1.f / 32.f);
  }
  __syncthreads();
  int e4 = threadIdx.x;                   // 256 float4 = 1024 floats
  const float4* W2v = (const float4*)W2;
  float4 acc = ((const float4*)bo)[e4];
#pragma unroll
  for (int h = 0; h < HH; h++) {
    float s = sh[h];
    float4 w = W2v[((size_t)b * HH + h) * 256 + e4];
    acc.x += s * w.x; acc.y += s * w.y; acc.z += s * w.z; acc.w += s * w.w;
  }
  ((float4*)out)[(size_t)row * 256 + e4] = acc;
}

extern "C" void kernel_launch(void* const* d_in, const int* in_sizes, int n_in,
                              void* d_out, int out_size, void* d_ws, size_t ws_size,
                              hipStream_t stream) {
  const float* query = (const float*)d_in[0];
  const float* key   = (const float*)d_in[1];
  const float* value = (const float*)d_in[2];
  const float* pos   = (const float*)d_in[3];
  const float* Wq = (const float*)d_in[4];
  const float* bq = (const float*)d_in[5];
  const float* Wk = (const float*)d_in[6];
  const float* bk = (const float*)d_in[7];
  const float* Wv = (const float*)d_in[8];
  const float* bv = (const float*)d_in[9];
  const float* Wp = (const float*)d_in[10];
  const float* Wo = (const float*)d_in[11];
  const float* bo = (const float*)d_in[12];
  const float* U  = (const float*)d_in[13];
  const float* V  = (const float*)d_in[14];
  float* out = (float*)d_out;

  char* ws = (char*)d_ws;
  size_t o = 0;
  auto take = [&](size_t bytes) -> char* {
    char* p = ws + o;
    o += (bytes + 255) & ~(size_t)255;
    return p;
  };
  float* keysum = (float*)take(BB * EE * 4);
  float* valsum = (float*)take(BB * EE * 4);
  float* Kproj  = (float*)take(BB * EE * 4);
  float* W2     = (float*)take((size_t)BB * HH * EE * 4);
  float* S1     = (float*)take((size_t)BB * HH * LL * 4);
  float* Dbuf   = (float*)take((size_t)BB * HH * LL * 4);
  float* chunks = (float*)take((size_t)BB * 64 * EE * 4);
  unsigned short* qbuf = (unsigned short*)take((size_t)BB * LL * EE * 2);
  unsigned short* rbuf = (unsigned short*)take((size_t)BB * LL * EE * 2);
  unsigned short* q16  = (unsigned short*)take((size_t)BB * LL * EE * 2);
  unsigned short* pe16 = (unsigned short*)take((size_t)BB * LL * EE * 2);
  unsigned short* wq16 = (unsigned short*)take((size_t)EE * EE * 2);
  unsigned short* wp16 = (unsigned short*)take((size_t)EE * EE * 2);

  // zero the atomic accumulators (keysum, valsum are adjacent)
  hipMemsetAsync(keysum, 0, (size_t)2 * BB * EE * 4, stream);

  prelude_kernel<<<SUMKV_BLOCKS + CAST_BLOCKS, 256, 0, stream>>>(
      query, pos, Wq, Wp, q16, pe16, wq16, wp16, key, value, keysum, valsum);
  small_kernel<<<40, 256, 0, stream>>>(keysum, valsum, Wk, bk, Wv, bv, Wo, Kproj, W2);
  gemm_kernel<<<dim3(EE / 128, BB * LL / 128, 2), 256, 0, stream>>>(
      q16, wq16, bq, qbuf, pe16, wp16, rbuf, chunks);
  scan2f_kernel<<<dim3(4, 64, BB), 256, 0, stream>>>(qbuf, rbuf, chunks, Kproj, U, V, S1, Dbuf);
  out_kernel<<<dim3(BB * LL), 256, 0, stream>>>(S1, Dbuf, W2, bo, out);
}

// Round 5
// 234.326 us; speedup vs baseline: 2.5860x; 2.5860x over previous
//
#include <hip/hip_runtime.h>

#define BB 2
#define LL 2048
#define EE 1024
#define HH 16
#define HDD 64

typedef __bf16 bf16x8 __attribute__((ext_vector_type(8)));
typedef float f32x4 __attribute__((ext_vector_type(4)));

__device__ __forceinline__ unsigned short f2bf(float f) {
  unsigned int x = __float_as_uint(f);
  return (unsigned short)((x + 0x7FFFu + ((x >> 16) & 1u)) >> 16);  // RNE
}

__device__ __forceinline__ float bf2f(unsigned short u) {
  return __uint_as_float((unsigned int)u << 16);
}

__device__ __forceinline__ void load_lds16(const void* g, void* l) {
  __builtin_amdgcn_global_load_lds(
      (const __attribute__((address_space(1))) void*)g,
      (__attribute__((address_space(3))) void*)l, 16, 0, 0);
}

// ---------------- prelude ----------------------------------------------------
// blocks 0..255   : column sums of key/value (16-row chunks, heavy -> first)
// blocks 256..1535: grid-stride cast fp32->bf16 of q, pe, Wq, Wp
#define SUMKV_BLOCKS 256
#define CAST_BLOCKS 1280
#define CAST_STRIDE (CAST_BLOCKS * 256)   // 327680 float4s per sweep
__global__ __launch_bounds__(256) void prelude_kernel(
    const float* __restrict__ q, const float* __restrict__ pe,
    const float* __restrict__ wq, const float* __restrict__ wp,
    unsigned short* __restrict__ q16, unsigned short* __restrict__ pe16,
    unsigned short* __restrict__ wq16, unsigned short* __restrict__ wp16,
    const float* __restrict__ key, const float* __restrict__ value,
    float* __restrict__ keysum, float* __restrict__ valsum) {
  if (blockIdx.x < SUMKV_BLOCKS) {
    int blk2 = blockIdx.x;                // (b, 128 chunks of 16 rows)
    int b = blk2 >> 7, ch = blk2 & 127;
    int tid = threadIdx.x;                // float4 index within E
    const float4* k4 = (const float4*)(key   + ((size_t)b * LL + ch * 16) * EE);
    const float4* v4 = (const float4*)(value + ((size_t)b * LL + ch * 16) * EE);
    float4 ak = make_float4(0.f, 0.f, 0.f, 0.f);
    float4 av = make_float4(0.f, 0.f, 0.f, 0.f);
#pragma unroll 8
    for (int i = 0; i < 16; i++) {
      float4 kk = k4[i * 256 + tid];
      float4 vv = v4[i * 256 + tid];
      ak.x += kk.x; ak.y += kk.y; ak.z += kk.z; ak.w += kk.w;
      av.x += vv.x; av.y += vv.y; av.z += vv.z; av.w += vv.w;
    }
    int e = tid * 4;
    atomicAdd(&keysum[b * EE + e + 0], ak.x);
    atomicAdd(&keysum[b * EE + e + 1], ak.y);
    atomicAdd(&keysum[b * EE + e + 2], ak.z);
    atomicAdd(&keysum[b * EE + e + 3], ak.w);
    atomicAdd(&valsum[b * EE + e + 0], av.x);
    atomicAdd(&valsum[b * EE + e + 1], av.y);
    atomicAdd(&valsum[b * EE + e + 2], av.z);
    atomicAdd(&valsum[b * EE + e + 3], av.w);
  } else {
    const int NQ4 = BB * LL * EE / 4;   // 1048576 float4s each for q, pe
    const int NW4 = EE * EE / 4;        // 262144 each for wq, wp
    int t = (blockIdx.x - SUMKV_BLOCKS) * 256 + threadIdx.x;
    float4 v[8]; unsigned short* dst[8]; int off[8];
#pragma unroll
    for (int k = 0; k < 8; k++) {
      int i = t + k * CAST_STRIDE;      // total = 8*327680 = 2621440 exactly
      const float* src;
      if (i < NQ4)                { src = q;  dst[k] = q16;  off[k] = i; }
      else if (i < 2 * NQ4)       { src = pe; dst[k] = pe16; off[k] = i - NQ4; }
      else if (i < 2 * NQ4 + NW4) { src = wq; dst[k] = wq16; off[k] = i - 2 * NQ4; }
      else                        { src = wp; dst[k] = wp16; off[k] = i - 2 * NQ4 - NW4; }
      v[k] = ((const float4*)src)[off[k]];
    }
#pragma unroll
    for (int k = 0; k < 8; k++) {
      ushort4 u;
      u.x = f2bf(v[k].x); u.y = f2bf(v[k].y); u.z = f2bf(v[k].z); u.w = f2bf(v[k].w);
      ((ushort4*)dst[k])[off[k]] = u;
    }
  }
}

// ---------------- project summed key/value: sum @ W.T + L*bias ---------------
// grid (BB*EE/4, 1, 2): one wave per output, 4096 waves total.
__global__ __launch_bounds__(256) void proj_kernel(
    const float* __restrict__ keysum, const float* __restrict__ valsum,
    const float* __restrict__ Wk, const float* __restrict__ bk,
    const float* __restrict__ Wv, const float* __restrict__ bv,
    float* __restrict__ Kproj, float* __restrict__ Vproj) {
  int wv = threadIdx.x >> 6, lane = threadIdx.x & 63;
  int idx = blockIdx.x * 4 + wv;          // [0, BB*EE)
  int b = idx >> 10, ep = idx & (EE - 1);
  const float* sum  = blockIdx.z ? valsum : keysum;
  const float* W    = blockIdx.z ? Wv : Wk;
  const float* bias = blockIdx.z ? bv : bk;
  float* outp       = blockIdx.z ? Vproj : Kproj;
  float acc = 0.f;
  for (int k = lane; k < EE; k += 64) acc += sum[b * EE + k] * W[ep * EE + k];
  for (int off = 32; off; off >>= 1) acc += __shfl_down(acc, off, 64);
  if (lane == 0) outp[b * EE + ep] = acc + (float)LL * bias[ep];
}

// ---------------- W2[b,h,e] = sum_d Vproj[b,h*64+d] * Wo[e, h*64+d] ----------
// grid (BB*HH*EE/4): one wave per output, 32768 waves total.
__global__ __launch_bounds__(256) void w2_kernel(
    const float* __restrict__ Vproj, const float* __restrict__ Wo,
    float* __restrict__ W2) {
  int wv = threadIdx.x >> 6, lane = threadIdx.x & 63;
  int idx = blockIdx.x * 4 + wv;          // [0, 32768)
  int e = idx & (EE - 1);
  int h = (idx >> 10) & (HH - 1);
  int b = idx >> 14;
  float acc = Vproj[b * EE + h * HDD + lane] * Wo[(size_t)e * EE + h * HDD + lane];
  for (int off = 32; off; off >>= 1) acc += __shfl_down(acc, off, 64);
  if (lane == 0) W2[((size_t)b * HH + h) * EE + e] = acc;
}

// ---------------- bf16 MFMA GEMM: Out[M,N] = X[M,K] @ W[N,K]^T (+bias) -------
// 128x128 tile, BK=32, global_load_lds width=16 staging (m97 structure).
// z=0 -> q projection (+bq); z=1 -> r projection + fused chunk row-sums.
// Outputs stored as bf16 (halves round-trip traffic; chunks stay fp32).
__global__ __launch_bounds__(256) void gemm_kernel(
    const unsigned short* __restrict__ q16, const unsigned short* __restrict__ wq16,
    const float* __restrict__ bq, unsigned short* __restrict__ qout,
    const unsigned short* __restrict__ pe16, const unsigned short* __restrict__ wp16,
    unsigned short* __restrict__ rout, float* __restrict__ chunks) {
  const int K = EE, N = EE;
  const unsigned short* X; const unsigned short* W; const float* bias;
  unsigned short* Out;
  if (blockIdx.z == 0) { X = q16;  W = wq16; bias = bq;      Out = qout; }
  else                 { X = pe16; W = wp16; bias = nullptr; Out = rout; }

  __shared__ __align__(16) unsigned short As[128 * 32];  // 8 KB
  __shared__ __align__(16) unsigned short Bs[128 * 32];

  const int tid = threadIdx.x;
  const int lane = tid & 63;
  const int wv = tid >> 6;
  const int wr = wv >> 1, wc = wv & 1;
  const int n0 = blockIdx.x * 128;
  const int m0 = blockIdx.y * 128;

  // staging: lane l of wave wv -> LDS ushort idx wv*512 + l*8 == row-major
  //   row = wv*16 + l/4, col = (l%4)*8 of a [128 x 32] tile (no padding)
  const int srow = wv * 16 + (lane >> 2);
  const int scol = (lane & 3) * 8;
  const unsigned short* gA = X + (size_t)(m0 + srow) * K + scol;
  const unsigned short* gB = W + (size_t)(n0 + srow) * K + scol;
  unsigned short* sA = As + wv * 512;   // wave-uniform base
  unsigned short* sB = Bs + wv * 512;

  f32x4 acc[4][4];
#pragma unroll
  for (int i = 0; i < 4; i++)
#pragma unroll
    for (int j = 0; j < 4; j++) acc[i][j] = (f32x4)0.0f;

  const int arow = wr * 64 + (lane & 15);
  const int brow = wc * 64 + (lane & 15);
  const int koff = (lane >> 4) * 8;

  for (int kk = 0; kk < K; kk += 32) {
    load_lds16(gA + kk,                   sA);
    load_lds16(gA + kk + (size_t)64 * K,  sA + 2048);
    load_lds16(gB + kk,                   sB);
    load_lds16(gB + kk + (size_t)64 * K,  sB + 2048);
    __syncthreads();
    bf16x8 af[4], bf[4];
#pragma unroll
    for (int i = 0; i < 4; i++) af[i] = *(const bf16x8*)&As[(arow + i * 16) * 32 + koff];
#pragma unroll
    for (int j = 0; j < 4; j++) bf[j] = *(const bf16x8*)&Bs[(brow + j * 16) * 32 + koff];
#pragma unroll
    for (int i = 0; i < 4; i++)
#pragma unroll
      for (int j = 0; j < 4; j++)
        acc[i][j] = __builtin_amdgcn_mfma_f32_16x16x32_bf16(af[i], bf[j], acc[i][j], 0, 0, 0);
    __syncthreads();
  }

  // epilogue: C/D layout col=lane&15, row=(lane>>4)*4+g  [verified m89/m91]
  const int rbase = m0 + wr * 64 + (lane >> 4) * 4;
  const int cbase = n0 + wc * 64 + (lane & 15);
#pragma unroll
  for (int i = 0; i < 4; i++) {
#pragma unroll
    for (int j = 0; j < 4; j++) {
      int col = cbase + j * 16;
      float badd = bias ? bias[col] : 0.f;
#pragma unroll
      for (int g = 0; g < 4; g++) {
        int row = rbase + i * 16 + g;
        Out[(size_t)row * N + col] = f2bf(acc[i][j][g] + badd);
      }
    }
  }

  // fused scan stage-1 for the r projection: 32-row chunk column sums (fp32).
  // Each (chunk, col) is owned by exactly one wave of one block -> plain store.
  if (blockIdx.z == 1) {
    int b = m0 >> 11;
    int ch0 = ((m0 & (LL - 1)) >> 5) + wr * 2;
#pragma unroll
    for (int cp = 0; cp < 2; cp++) {
#pragma unroll
      for (int j = 0; j < 4; j++) {
        float s = 0.f;
#pragma unroll
        for (int i = cp * 2; i < cp * 2 + 2; i++)
#pragma unroll
          for (int g = 0; g < 4; g++) s += acc[i][j][g];
        s += __shfl_down(s, 32, 64);
        s += __shfl_down(s, 16, 64);
        if (lane < 16) {
          int col = n0 + wc * 64 + j * 16 + lane;
          chunks[((size_t)b * 64 + ch0 + cp) * EE + col] = s;
        }
      }
    }
  }
}

// ---------------- fused scan + score ----------------------------------------
// P[m] = prefix of r rows (in registers).  D[m] = (q_{L-1-m}+V) . P[m]
// S1[p] = (q_p+U).Kproj + (q_p+V).P[L]     (per-head dots over 64 lanes)
// grid (4 head-groups, 64 chunks, BB), block 256. qbuf/rbuf are bf16.
__global__ __launch_bounds__(256) void scan2f_kernel(
    const unsigned short* __restrict__ qbuf, const unsigned short* __restrict__ rbuf,
    const float* __restrict__ chunks, const float* __restrict__ Kproj,
    const float* __restrict__ U, const float* __restrict__ V,
    float* __restrict__ S1, float* __restrict__ Dbuf) {
  int tid = threadIdx.x, lane = tid & 63;
  int hg = blockIdx.x, ch = blockIdx.y, b = blockIdx.z;
  int e = hg * 256 + tid;
  int h = hg * 4 + (tid >> 6);
  float pre = 0.f, tot = 0.f;
  for (int c = 0; c < 64; c++) {           // 512 KB buffer, L2-resident
    float cs = chunks[((size_t)b * 64 + c) * EE + e];
    tot += cs;
    if (c < ch) pre += cs;
  }
  float kp = Kproj[b * EE + e], Ue = U[e], Ve = V[e];
  float run = pre;                          // == P[ch*32][e]
  size_t hoff = ((size_t)b * HH + h) * LL;
#pragma unroll 4
  for (int i = 0; i < 32; i++) {
    int m = ch * 32 + i;
    int p = LL - 1 - m;
    float qv = bf2f(qbuf[((size_t)b * LL + p) * EE + e]);
    float rv = bf2f(rbuf[((size_t)b * LL + m) * EE + e]);
    float tq = qv + Ve;
    float d = tq * run;                     // run == P[m]
    float s = tq * tot + (qv + Ue) * kp;
#pragma unroll
    for (int off = 32; off; off >>= 1) {
      d += __shfl_down(d, off, 64);
      s += __shfl_down(s, off, 64);
    }
    if (lane == 0) { Dbuf[hoff + m] = d; S1[hoff + p] = s; }
    run += rv;
  }
}

// ---------------- output: out[b,p,:] = sum_h S[b,h,p]*W2[b,h,:] + bo ---------
// S[b,h,p] = (S1[p] - D[L-1-p] + D[L-2-p]) / 32
__global__ __launch_bounds__(256) void out_kernel(
    const float* __restrict__ S1, const float* __restrict__ Dbuf,
    const float* __restrict__ W2, const float* __restrict__ bo,
    float* __restrict__ out) {
  int row = blockIdx.x;                   // [0, BB*LL)
  int b = row >> 11, p = row & (LL - 1);
  __shared__ float sh[HH];
  if (threadIdx.x < HH) {
    int h = threadIdx.x;
    size_t hoff = ((size_t)b * HH + h) * LL;
    float s1 = S1[hoff + p];
    float d1 = Dbuf[hoff + (LL - 1 - p)];
    float d2 = (p == LL - 1) ? 0.f : Dbuf[hoff + (LL - 2 - p)];
    sh[h] = (s1 - d1 + d2) * (1.f / 32.f);
  }
  __syncthreads();
  int e4 = threadIdx.x;                   // 256 float4 = 1024 floats
  const float4* W2v = (const float4*)W2;
  float4 acc = ((const float4*)bo)[e4];
#pragma unroll
  for (int h = 0; h < HH; h++) {
    float s = sh[h];
    float4 w = W2v[((size_t)b * HH + h) * 256 + e4];
    acc.x += s * w.x; acc.y += s * w.y; acc.z += s * w.z; acc.w += s * w.w;
  }
  ((float4*)out)[(size_t)row * 256 + e4] = acc;
}

extern "C" void kernel_launch(void* const* d_in, const int* in_sizes, int n_in,
                              void* d_out, int out_size, void* d_ws, size_t ws_size,
                              hipStream_t stream) {
  const float* query = (const float*)d_in[0];
  const float* key   = (const float*)d_in[1];
  const float* value = (const float*)d_in[2];
  const float* pos   = (const float*)d_in[3];
  const float* Wq = (const float*)d_in[4];
  const float* bq = (const float*)d_in[5];
  const float* Wk = (const float*)d_in[6];
  const float* bk = (const float*)d_in[7];
  const float* Wv = (const float*)d_in[8];
  const float* bv = (const float*)d_in[9];
  const float* Wp = (const float*)d_in[10];
  const float* Wo = (const float*)d_in[11];
  const float* bo = (const float*)d_in[12];
  const float* U  = (const float*)d_in[13];
  const float* V  = (const float*)d_in[14];
  float* out = (float*)d_out;

  char* ws = (char*)d_ws;
  size_t o = 0;
  auto take = [&](size_t bytes) -> char* {
    char* p = ws + o;
    o += (bytes + 255) & ~(size_t)255;
    return p;
  };
  float* keysum = (float*)take(BB * EE * 4);
  float* valsum = (float*)take(BB * EE * 4);
  float* Kproj  = (float*)take(BB * EE * 4);
  float* Vproj  = (float*)take(BB * EE * 4);
  float* W2     = (float*)take((size_t)BB * HH * EE * 4);
  float* S1     = (float*)take((size_t)BB * HH * LL * 4);
  float* Dbuf   = (float*)take((size_t)BB * HH * LL * 4);
  float* chunks = (float*)take((size_t)BB * 64 * EE * 4);
  unsigned short* qbuf = (unsigned short*)take((size_t)BB * LL * EE * 2);
  unsigned short* rbuf = (unsigned short*)take((size_t)BB * LL * EE * 2);
  unsigned short* q16  = (unsigned short*)take((size_t)BB * LL * EE * 2);
  unsigned short* pe16 = (unsigned short*)take((size_t)BB * LL * EE * 2);
  unsigned short* wq16 = (unsigned short*)take((size_t)EE * EE * 2);
  unsigned short* wp16 = (unsigned short*)take((size_t)EE * EE * 2);

  // zero the atomic accumulators (keysum, valsum are adjacent)
  hipMemsetAsync(keysum, 0, (size_t)2 * BB * EE * 4, stream);

  prelude_kernel<<<SUMKV_BLOCKS + CAST_BLOCKS, 256, 0, stream>>>(
      query, pos, Wq, Wp, q16, pe16, wq16, wp16, key, value, keysum, valsum);
  proj_kernel<<<dim3(BB * EE / 4, 1, 2), 256, 0, stream>>>(
      keysum, valsum, Wk, bk, Wv, bv, Kproj, Vproj);
  w2_kernel<<<dim3(BB * HH * EE / 4), 256, 0, stream>>>(Vproj, Wo, W2);
  gemm_kernel<<<dim3(EE / 128, BB * LL / 128, 2), 256, 0, stream>>>(
      q16, wq16, bq, qbuf, pe16, wp16, rbuf, chunks);
  scan2f_kernel<<<dim3(4, 64, BB), 256, 0, stream>>>(qbuf, rbuf, chunks, Kproj, U, V, S1, Dbuf);
  out_kernel<<<dim3(BB * LL), 256, 0, stream>>>(S1, Dbuf, W2, bo, out);
}

// Round 6
// 222.766 us; speedup vs baseline: 2.7202x; 1.0519x over previous
//
#include <hip/hip_runtime.h>

#define BB 2
#define LL 2048
#define EE 1024
#define HH 16
#define HDD 64

typedef __bf16 bf16x8 __attribute__((ext_vector_type(8)));
typedef float f32x4 __attribute__((ext_vector_type(4)));

__device__ __forceinline__ unsigned short f2bf(float f) {
  unsigned int x = __float_as_uint(f);
  return (unsigned short)((x + 0x7FFFu + ((x >> 16) & 1u)) >> 16);  // RNE
}

__device__ __forceinline__ float bf2f(unsigned short u) {
  return __uint_as_float((unsigned int)u << 16);
}

__device__ __forceinline__ void load_lds16(const void* g, void* l) {
  __builtin_amdgcn_global_load_lds(
      (const __attribute__((address_space(1))) void*)g,
      (__attribute__((address_space(3))) void*)l, 16, 0, 0);
}

// ---------------- prelude ----------------------------------------------------
// blocks 0..255   : column sums of key/value (16-row chunks, heavy -> first)
// blocks 256..1535: grid-stride cast fp32->bf16 of q, pe, Wq, Wp
#define SUMKV_BLOCKS 256
#define CAST_BLOCKS 1280
#define CAST_STRIDE (CAST_BLOCKS * 256)   // 327680 float4s per sweep
__global__ __launch_bounds__(256) void prelude_kernel(
    const float* __restrict__ q, const float* __restrict__ pe,
    const float* __restrict__ wq, const float* __restrict__ wp,
    unsigned short* __restrict__ q16, unsigned short* __restrict__ pe16,
    unsigned short* __restrict__ wq16, unsigned short* __restrict__ wp16,
    const float* __restrict__ key, const float* __restrict__ value,
    float* __restrict__ keysum, float* __restrict__ valsum) {
  if (blockIdx.x < SUMKV_BLOCKS) {
    int blk2 = blockIdx.x;                // (b, 128 chunks of 16 rows)
    int b = blk2 >> 7, ch = blk2 & 127;
    int tid = threadIdx.x;                // float4 index within E
    const float4* k4 = (const float4*)(key   + ((size_t)b * LL + ch * 16) * EE);
    const float4* v4 = (const float4*)(value + ((size_t)b * LL + ch * 16) * EE);
    float4 ak = make_float4(0.f, 0.f, 0.f, 0.f);
    float4 av = make_float4(0.f, 0.f, 0.f, 0.f);
#pragma unroll 8
    for (int i = 0; i < 16; i++) {
      float4 kk = k4[i * 256 + tid];
      float4 vv = v4[i * 256 + tid];
      ak.x += kk.x; ak.y += kk.y; ak.z += kk.z; ak.w += kk.w;
      av.x += vv.x; av.y += vv.y; av.z += vv.z; av.w += vv.w;
    }
    int e = tid * 4;
    atomicAdd(&keysum[b * EE + e + 0], ak.x);
    atomicAdd(&keysum[b * EE + e + 1], ak.y);
    atomicAdd(&keysum[b * EE + e + 2], ak.z);
    atomicAdd(&keysum[b * EE + e + 3], ak.w);
    atomicAdd(&valsum[b * EE + e + 0], av.x);
    atomicAdd(&valsum[b * EE + e + 1], av.y);
    atomicAdd(&valsum[b * EE + e + 2], av.z);
    atomicAdd(&valsum[b * EE + e + 3], av.w);
  } else {
    const int NQ4 = BB * LL * EE / 4;   // 1048576 float4s each for q, pe
    const int NW4 = EE * EE / 4;        // 262144 each for wq, wp
    int t = (blockIdx.x - SUMKV_BLOCKS) * 256 + threadIdx.x;
    float4 v[8]; unsigned short* dst[8]; int off[8];
#pragma unroll
    for (int k = 0; k < 8; k++) {
      int i = t + k * CAST_STRIDE;      // total = 8*327680 = 2621440 exactly
      const float* src;
      if (i < NQ4)                { src = q;  dst[k] = q16;  off[k] = i; }
      else if (i < 2 * NQ4)       { src = pe; dst[k] = pe16; off[k] = i - NQ4; }
      else if (i < 2 * NQ4 + NW4) { src = wq; dst[k] = wq16; off[k] = i - 2 * NQ4; }
      else                        { src = wp; dst[k] = wp16; off[k] = i - 2 * NQ4 - NW4; }
      v[k] = ((const float4*)src)[off[k]];
    }
#pragma unroll
    for (int k = 0; k < 8; k++) {
      ushort4 u;
      u.x = f2bf(v[k].x); u.y = f2bf(v[k].y); u.z = f2bf(v[k].z); u.w = f2bf(v[k].w);
      ((ushort4*)dst[k])[off[k]] = u;
    }
  }
}

// ---------------- project summed key/value: sum @ W.T + L*bias ---------------
// grid (BB*EE/4, 1, 2): one wave per output, 4096 waves total.
__global__ __launch_bounds__(256) void proj_kernel(
    const float* __restrict__ keysum, const float* __restrict__ valsum,
    const float* __restrict__ Wk, const float* __restrict__ bk,
    const float* __restrict__ Wv, const float* __restrict__ bv,
    float* __restrict__ Kproj, float* __restrict__ Vproj) {
  int wv = threadIdx.x >> 6, lane = threadIdx.x & 63;
  int idx = blockIdx.x * 4 + wv;          // [0, BB*EE)
  int b = idx >> 10, ep = idx & (EE - 1);
  const float* sum  = blockIdx.z ? valsum : keysum;
  const float* W    = blockIdx.z ? Wv : Wk;
  const float* bias = blockIdx.z ? bv : bk;
  float* outp       = blockIdx.z ? Vproj : Kproj;
  float acc = 0.f;
  for (int k = lane; k < EE; k += 64) acc += sum[b * EE + k] * W[ep * EE + k];
  for (int off = 32; off; off >>= 1) acc += __shfl_down(acc, off, 64);
  if (lane == 0) outp[b * EE + ep] = acc + (float)LL * bias[ep];
}

// ---------------- bf16 MFMA GEMM + fused w2 slice ----------------------------
// grid (32, 8, 3): x = m-tile, y = n-tile (transposed so same-m blocks sit at
// linear-ID stride 32 == 0 mod 8 -> same XCD -> A-tiles fetched once per XCD).
// z=0 -> q projection (+bq); z=1 -> r projection + fused chunk row-sums.
// z=2 -> w2 slice: W2[b,h,e] = sum_d Vproj[b,h*64+d] * Wo[e, h*64+d]
// GEMM outputs stored bf16 (halves round-trip); chunks stay fp32.
__global__ __launch_bounds__(256) void gemm_kernel(
    const unsigned short* __restrict__ q16, const unsigned short* __restrict__ wq16,
    const float* __restrict__ bq, unsigned short* __restrict__ qout,
    const unsigned short* __restrict__ pe16, const unsigned short* __restrict__ wp16,
    unsigned short* __restrict__ rout, float* __restrict__ chunks,
    const float* __restrict__ Vproj, const float* __restrict__ Wo,
    float* __restrict__ W2) {
  const int tid = threadIdx.x;
  const int lane = tid & 63;
  const int wv = tid >> 6;

  if (blockIdx.z == 2) {
    // ---- w2 slice: 256 blocks = 1024 waves, 32 outputs per wave ----
    int bid = blockIdx.x + 32 * blockIdx.y;   // 0..255
    int wslot = bid * 4 + wv;                 // 0..1023
    int base = wslot * 32;                    // first output idx
    int b = base >> 14;
    int h = (base >> 10) & (HH - 1);
    int e0 = base & (EE - 1);                 // 32 outputs stay in one (b,h)
    float vp = Vproj[b * EE + h * HDD + lane];
    const float* wo = Wo + (size_t)e0 * EE + h * HDD + lane;
    for (int r = 0; r < 32; r++) {
      float acc = vp * wo[(size_t)r * EE];
      for (int off = 32; off; off >>= 1) acc += __shfl_down(acc, off, 64);
      if (lane == 0) W2[((size_t)b * HH + h) * EE + e0 + r] = acc;
    }
    return;
  }

  const int K = EE, N = EE;
  const unsigned short* X; const unsigned short* W; const float* bias;
  unsigned short* Out;
  if (blockIdx.z == 0) { X = q16;  W = wq16; bias = bq;      Out = qout; }
  else                 { X = pe16; W = wp16; bias = nullptr; Out = rout; }

  __shared__ __align__(16) unsigned short As[128 * 32];  // 8 KB
  __shared__ __align__(16) unsigned short Bs[128 * 32];

  const int wr = wv >> 1, wc = wv & 1;
  const int m0 = blockIdx.x * 128;
  const int n0 = blockIdx.y * 128;

  // staging: lane l of wave wv -> LDS ushort idx wv*512 + l*8 == row-major
  //   row = wv*16 + l/4, col = (l%4)*8 of a [128 x 32] tile (no padding)
  const int srow = wv * 16 + (lane >> 2);
  const int scol = (lane & 3) * 8;
  const unsigned short* gA = X + (size_t)(m0 + srow) * K + scol;
  const unsigned short* gB = W + (size_t)(n0 + srow) * K + scol;
  unsigned short* sA = As + wv * 512;   // wave-uniform base
  unsigned short* sB = Bs + wv * 512;

  f32x4 acc[4][4];
#pragma unroll
  for (int i = 0; i < 4; i++)
#pragma unroll
    for (int j = 0; j < 4; j++) acc[i][j] = (f32x4)0.0f;

  const int arow = wr * 64 + (lane & 15);
  const int brow = wc * 64 + (lane & 15);
  const int koff = (lane >> 4) * 8;

  for (int kk = 0; kk < K; kk += 32) {
    load_lds16(gA + kk,                   sA);
    load_lds16(gA + kk + (size_t)64 * K,  sA + 2048);
    load_lds16(gB + kk,                   sB);
    load_lds16(gB + kk + (size_t)64 * K,  sB + 2048);
    __syncthreads();
    bf16x8 af[4], bf[4];
#pragma unroll
    for (int i = 0; i < 4; i++) af[i] = *(const bf16x8*)&As[(arow + i * 16) * 32 + koff];
#pragma unroll
    for (int j = 0; j < 4; j++) bf[j] = *(const bf16x8*)&Bs[(brow + j * 16) * 32 + koff];
#pragma unroll
    for (int i = 0; i < 4; i++)
#pragma unroll
      for (int j = 0; j < 4; j++)
        acc[i][j] = __builtin_amdgcn_mfma_f32_16x16x32_bf16(af[i], bf[j], acc[i][j], 0, 0, 0);
    __syncthreads();
  }

  // epilogue: C/D layout col=lane&15, row=(lane>>4)*4+g  [verified m89/m91]
  const int rbase = m0 + wr * 64 + (lane >> 4) * 4;
  const int cbase = n0 + wc * 64 + (lane & 15);
#pragma unroll
  for (int i = 0; i < 4; i++) {
#pragma unroll
    for (int j = 0; j < 4; j++) {
      int col = cbase + j * 16;
      float badd = bias ? bias[col] : 0.f;
#pragma unroll
      for (int g = 0; g < 4; g++) {
        int row = rbase + i * 16 + g;
        Out[(size_t)row * N + col] = f2bf(acc[i][j][g] + badd);
      }
    }
  }

  // fused scan stage-1 for the r projection: 32-row chunk column sums (fp32).
  // Each (chunk, col) is owned by exactly one wave of one block -> plain store.
  if (blockIdx.z == 1) {
    int b = m0 >> 11;
    int ch0 = ((m0 & (LL - 1)) >> 5) + wr * 2;
#pragma unroll
    for (int cp = 0; cp < 2; cp++) {
#pragma unroll
      for (int j = 0; j < 4; j++) {
        float s = 0.f;
#pragma unroll
        for (int i = cp * 2; i < cp * 2 + 2; i++)
#pragma unroll
          for (int g = 0; g < 4; g++) s += acc[i][j][g];
        s += __shfl_down(s, 32, 64);
        s += __shfl_down(s, 16, 64);
        if (lane < 16) {
          int col = n0 + wc * 64 + j * 16 + lane;
          chunks[((size_t)b * 64 + ch0 + cp) * EE + col] = s;
        }
      }
    }
  }
}

// ---------------- fused scan + score ----------------------------------------
// P[m] = prefix of r rows (in registers).  D[m] = (q_{L-1-m}+V) . P[m]
// S1[p] = (q_p+U).Kproj + (q_p+V).P[L]     (per-head dots over 64 lanes)
// grid (4 head-groups, 64 chunks, BB), block 256. qbuf/rbuf are bf16.
__global__ __launch_bounds__(256) void scan2f_kernel(
    const unsigned short* __restrict__ qbuf, const unsigned short* __restrict__ rbuf,
    const float* __restrict__ chunks, const float* __restrict__ Kproj,
    const float* __restrict__ U, const float* __restrict__ V,
    float* __restrict__ S1, float* __restrict__ Dbuf) {
  int tid = threadIdx.x, lane = tid & 63;
  int hg = blockIdx.x, ch = blockIdx.y, b = blockIdx.z;
  int e = hg * 256 + tid;
  int h = hg * 4 + (tid >> 6);
  float pre = 0.f, tot = 0.f;
  for (int c = 0; c < 64; c++) {           // 512 KB buffer, L2-resident
    float cs = chunks[((size_t)b * 64 + c) * EE + e];
    tot += cs;
    if (c < ch) pre += cs;
  }
  float kp = Kproj[b * EE + e], Ue = U[e], Ve = V[e];
  float run = pre;                          // == P[ch*32][e]
  size_t hoff = ((size_t)b * HH + h) * LL;
#pragma unroll 4
  for (int i = 0; i < 32; i++) {
    int m = ch * 32 + i;
    int p = LL - 1 - m;
    float qv = bf2f(qbuf[((size_t)b * LL + p) * EE + e]);
    float rv = bf2f(rbuf[((size_t)b * LL + m) * EE + e]);
    float tq = qv + Ve;
    float d = tq * run;                     // run == P[m]
    float s = tq * tot + (qv + Ue) * kp;
#pragma unroll
    for (int off = 32; off; off >>= 1) {
      d += __shfl_down(d, off, 64);
      s += __shfl_down(s, off, 64);
    }
    if (lane == 0) { Dbuf[hoff + m] = d; S1[hoff + p] = s; }
    run += rv;
  }
}

// ---------------- output: out[b,p,:] = sum_h S[b,h,p]*W2[b,h,:] + bo ---------
// S[b,h,p] = (S1[p] - D[L-1-p] + D[L-2-p]) / 32
// 512 blocks x 8 rows; W2[b] slice cached in 64 VGPRs/thread (16 float4).
__global__ __launch_bounds__(256) void out_kernel(
    const float* __restrict__ S1, const float* __restrict__ Dbuf,
    const float* __restrict__ W2, const float* __restrict__ bo,
    float* __restrict__ out) {
  int row0 = blockIdx.x * 8;              // [0, BB*LL)
  int b = row0 >> 11, p0 = row0 & (LL - 1);
  int tid = threadIdx.x;
  __shared__ float sh[8][HH];
  if (tid < 128) {
    int rr = tid >> 4, h = tid & 15;
    int p = p0 + rr;
    size_t hoff = ((size_t)b * HH + h) * LL;
    float s1 = S1[hoff + p];
    float d1 = Dbuf[hoff + (LL - 1 - p)];
    float d2 = (p == LL - 1) ? 0.f : Dbuf[hoff + (LL - 2 - p)];
    sh[rr][h] = (s1 - d1 + d2) * (1.f / 32.f);
  }
  float4 w2r[HH];
#pragma unroll
  for (int h = 0; h < HH; h++)
    w2r[h] = ((const float4*)(W2 + ((size_t)b * HH + h) * EE))[tid];
  float4 bo4 = ((const float4*)bo)[tid];
  __syncthreads();
#pragma unroll
  for (int rr = 0; rr < 8; rr++) {
    float4 acc = bo4;
#pragma unroll
    for (int h = 0; h < HH; h++) {
      float s = sh[rr][h];
      acc.x += s * w2r[h].x; acc.y += s * w2r[h].y;
      acc.z += s * w2r[h].z; acc.w += s * w2r[h].w;
    }
    ((float4*)out)[(size_t)(row0 + rr) * 256 + tid] = acc;
  }
}

extern "C" void kernel_launch(void* const* d_in, const int* in_sizes, int n_in,
                              void* d_out, int out_size, void* d_ws, size_t ws_size,
                              hipStream_t stream) {
  const float* query = (const float*)d_in[0];
  const float* key   = (const float*)d_in[1];
  const float* value = (const float*)d_in[2];
  const float* pos   = (const float*)d_in[3];
  const float* Wq = (const float*)d_in[4];
  const float* bq = (const float*)d_in[5];
  const float* Wk = (const float*)d_in[6];
  const float* bk = (const float*)d_in[7];
  const float* Wv = (const float*)d_in[8];
  const float* bv = (const float*)d_in[9];
  const float* Wp = (const float*)d_in[10];
  const float* Wo = (const float*)d_in[11];
  const float* bo = (const float*)d_in[12];
  const float* U  = (const float*)d_in[13];
  const float* V  = (const float*)d_in[14];
  float* out = (float*)d_out;

  char* ws = (char*)d_ws;
  size_t o = 0;
  auto take = [&](size_t bytes) -> char* {
    char* p = ws + o;
    o += (bytes + 255) & ~(size_t)255;
    return p;
  };
  float* keysum = (float*)take(BB * EE * 4);
  float* valsum = (float*)take(BB * EE * 4);
  float* Kproj  = (float*)take(BB * EE * 4);
  float* Vproj  = (float*)take(BB * EE * 4);
  float* W2     = (float*)take((size_t)BB * HH * EE * 4);
  float* S1     = (float*)take((size_t)BB * HH * LL * 4);
  float* Dbuf   = (float*)take((size_t)BB * HH * LL * 4);
  float* chunks = (float*)take((size_t)BB * 64 * EE * 4);
  unsigned short* qbuf = (unsigned short*)take((size_t)BB * LL * EE * 2);
  unsigned short* rbuf = (unsigned short*)take((size_t)BB * LL * EE * 2);
  unsigned short* q16  = (unsigned short*)take((size_t)BB * LL * EE * 2);
  unsigned short* pe16 = (unsigned short*)take((size_t)BB * LL * EE * 2);
  unsigned short* wq16 = (unsigned short*)take((size_t)EE * EE * 2);
  unsigned short* wp16 = (unsigned short*)take((size_t)EE * EE * 2);

  // zero the atomic accumulators (keysum, valsum are adjacent)
  hipMemsetAsync(keysum, 0, (size_t)2 * BB * EE * 4, stream);

  prelude_kernel<<<SUMKV_BLOCKS + CAST_BLOCKS, 256, 0, stream>>>(
      query, pos, Wq, Wp, q16, pe16, wq16, wp16, key, value, keysum, valsum);
  proj_kernel<<<dim3(BB * EE / 4, 1, 2), 256, 0, stream>>>(
      keysum, valsum, Wk, bk, Wv, bv, Kproj, Vproj);
  gemm_kernel<<<dim3(BB * LL / 128, EE / 128, 3), 256, 0, stream>>>(
      q16, wq16, bq, qbuf, pe16, wp16, rbuf, chunks, Vproj, Wo, W2);
  scan2f_kernel<<<dim3(4, 64, BB), 256, 0, stream>>>(qbuf, rbuf, chunks, Kproj, U, V, S1, Dbuf);
  out_kernel<<<dim3(BB * LL / 8), 256, 0, stream>>>(S1, Dbuf, W2, bo, out);
}